// Round 4
// baseline (1055.834 us; speedup 1.0000x reference)
//
#include <hip/hip_runtime.h>
#include <hip/hip_bf16.h>

// FSNet: embed -> bi-GRU(2) encoder -> broadcast -> bi-GRU(2) decoder
//        -> fc head (64x20) + reconstruction GEMM (64x100x10000)
// R4 changes vs R3 (1004.6 us):
//  - gru_scan: time loop unrolled x2 with TWO named gi register sets (prefetch
//    depth ~2 steps; loads stay in flight across the lgkmcnt-only barrier) and
//    gate MFMA chains split 4-deep -> 2x 2-deep (halved dep latency).
//  - gemm_bt: ADIRECT path (gemm1/gemm_d1/rec) loads A fragments global->VGPR
//    (A is L2/L3-resident), removing A LDS staging + halving barrier drain.
// Numerics: fp32 accumulation order change in scan gates only (within tolerance).

typedef __bf16 bf16x8 __attribute__((ext_vector_type(8)));
typedef float f32x4 __attribute__((ext_vector_type(4)));

__device__ __forceinline__ ushort f2bf(float f) {
    __hip_bfloat16 h = __float2bfloat16(f);   // RNE
    return *reinterpret_cast<ushort*>(&h);
}
__device__ __forceinline__ float sigm(float x) {
    return 1.f / (1.f + __expf(-x));
}
__device__ __forceinline__ float tanh_f(float x) {
    x = fminf(fmaxf(x, -15.f), 15.f);
    float e = __expf(2.f * x);
    return (e - 1.f) / (e + 1.f);
}
// LDS-only barrier: orders ds_write -> ds_read without draining vmcnt.
__device__ __forceinline__ void lds_barrier() {
    asm volatile("s_waitcnt lgkmcnt(0)" ::: "memory");
    __builtin_amdgcn_s_barrier();
}
// async global->LDS, 16B per lane; lds base is wave-uniform, HW adds lane*16.
__device__ __forceinline__ void gload16(const void* g, void* l) {
    __builtin_amdgcn_global_load_lds(
        (const __attribute__((address_space(1))) unsigned int*)g,
        (__attribute__((address_space(3))) unsigned int*)l, 16, 0, 0);
}

// ---------------------------------------------------------------- fp32 -> bf16, 5 segments, one dispatch
// dst layout (elements): [eWih0:98304][eWih1:196608][dWih0:393216][dWih1:196608][recW:2560000]
__global__ __launch_bounds__(256) void cvt_all(const float* __restrict__ s0,
                                               const float* __restrict__ s1,
                                               const float* __restrict__ s2,
                                               const float* __restrict__ s3,
                                               const float* __restrict__ s4,
                                               ushort* __restrict__ dst) {
    int i = blockIdx.x * 256 + threadIdx.x;         // 430592 threads exactly
    size_t e = (size_t)i * 8;
    const float* s; size_t off;
    if      (e < 98304)  { s = s0; off = e; }
    else if (e < 294912) { s = s1; off = e - 98304; }
    else if (e < 688128) { s = s2; off = e - 294912; }
    else if (e < 884736) { s = s3; off = e - 688128; }
    else                 { s = s4; off = e - 884736; }
    const float* p = s + off;
    ushort4 lo, hi;
    lo.x = f2bf(p[0]); lo.y = f2bf(p[1]); lo.z = f2bf(p[2]); lo.w = f2bf(p[3]);
    hi.x = f2bf(p[4]); hi.y = f2bf(p[5]); hi.z = f2bf(p[6]); hi.w = f2bf(p[7]);
    ushort* d = dst + e;
    *reinterpret_cast<ushort4*>(d)     = lo;
    *reinterpret_cast<ushort4*>(d + 4) = hi;
}

// ---------------------------------------------------------------- GEMM C = A @ W.T + bias (fp32 out)
// A: [M][K] bf16. Paths: AGATHER (emb rows via x, reg-staged to LDS),
// ADIRECT (A fragments global->VGPR, requires M%128==0 vs grid; A L2-resident),
// default (A via global_load_lds). W: [N][K] bf16 via global_load_lds.
// 128x128 tile, 4 waves, mfma 16x16x32 bf16. LDS linear [128][64]u16 with
// byte ^= ((row&7)<<4) swizzle (write via pre-swizzled gload source; read swizzled).
// OOB tile rows (N tail) read garbage from within ws -- never stored.
// bhh_fold (optional, N=768 GRU case): adds bhh[n] for gate cols (n%384)<256 (r,z biases).
template <bool AGATHER, bool ADIRECT, bool NTC>
__global__ __launch_bounds__(256) void gemm_bt(const ushort* __restrict__ A, int lda,
                                               const ushort* __restrict__ W, int ldw,
                                               const float* __restrict__ bias,
                                               const float* __restrict__ bhh_fold,
                                               float* __restrict__ C, int ldc,
                                               int M, int N, int K,
                                               const float* __restrict__ embp,
                                               const int* __restrict__ xidx) {
    __shared__ __align__(16) ushort As[128 * 64];   // linear, 16KB (unused in ADIRECT)
    __shared__ __align__(16) ushort Ws[128 * 64];
    const int tid = threadIdx.x;
    const int lane = tid & 63, wave = tid >> 6;
    const int n0 = blockIdx.x * 128, m0 = blockIdx.y * 128;
    const int wm = (wave >> 1) * 64, wn = (wave & 1) * 64;
    const int lm = lane & 15, kq = lane >> 4;
    const int swz = (lm & 7) << 4;                  // read-side XOR (row&7 == lm&7)
    f32x4 acc[4][4] = {};

    for (int kb = 0; kb < K; kb += 64) {
        bf16x8 areg[4][2];
        if (ADIRECT) {
            // A fragments straight from global (L2-resident); in flight until the
            // barrier drain, consumed from regs after it.
            #pragma unroll
            for (int tt = 0; tt < 4; ++tt)
                #pragma unroll
                for (int k2 = 0; k2 < 2; ++k2)
                    areg[tt][k2] = *reinterpret_cast<const bf16x8*>(
                        &A[(size_t)(m0 + wm + tt * 16 + lm) * lda + kb + k2 * 32 + kq * 8]);
        } else if (AGATHER) {
            // A rows gathered from emb via x (fp32 -> bf16), swizzled ds_write.
            #pragma unroll
            for (int it = 0; it < 8; ++it) {        // 2048 float4 chunks
                int chunk = it * 256 + tid;
                int row = chunk >> 4, kc = chunk & 15;
                int xi = xidx[m0 + row];
                xi = xi > 9999 ? 9999 : (xi < 0 ? 0 : xi);
                float4 a4 = *reinterpret_cast<const float4*>(&embp[(size_t)xi * 128 + kb + kc * 4]);
                ushort4 b4;
                b4.x = f2bf(a4.x); b4.y = f2bf(a4.y); b4.z = f2bf(a4.z); b4.w = f2bf(a4.w);
                int sb = (row * 128 + kc * 8) ^ ((row & 7) << 4);
                *reinterpret_cast<ushort4*>((char*)As + sb) = b4;
            }
        } else {
            #pragma unroll
            for (int seg = 0; seg < 4; ++seg) {     // 4KB per wave, 1KB per call
                int chunk = (wave * 4 + seg) * 64 + lane;   // 0..1023
                int L  = chunk * 16;                         // linear LDS byte
                int Ls = L ^ (((L >> 7) & 7) << 4);          // logical byte stored here
                int row = Ls >> 7, colb = Ls & 127;
                gload16(&A[(size_t)(m0 + row) * lda + kb + (colb >> 1)],
                        (char*)As + (wave * 4 + seg) * 1024);
            }
        }
        #pragma unroll
        for (int seg = 0; seg < 4; ++seg) {         // W bf16 via gload_lds
            int chunk = (wave * 4 + seg) * 64 + lane;
            int L  = chunk * 16;
            int Ls = L ^ (((L >> 7) & 7) << 4);
            int row = Ls >> 7, colb = Ls & 127;
            gload16(&W[(size_t)(n0 + row) * ldw + kb + (colb >> 1)],
                    (char*)Ws + (wave * 4 + seg) * 1024);
        }
        __syncthreads();                            // drains vmcnt (gload + areg) + lgkmcnt
        #pragma unroll
        for (int k2 = 0; k2 < 2; ++k2) {
            bf16x8 af[4], wf[4];
            #pragma unroll
            for (int tt = 0; tt < 4; ++tt) {
                if (ADIRECT) {
                    af[tt] = areg[tt][k2];
                } else {
                    int Pa = (wm + tt * 16 + lm) * 128 + k2 * 64 + kq * 16;
                    af[tt] = *reinterpret_cast<const bf16x8*>((const char*)As + (Pa ^ swz));
                }
                int Pw = (wn + tt * 16 + lm) * 128 + k2 * 64 + kq * 16;
                wf[tt] = *reinterpret_cast<const bf16x8*>((const char*)Ws + (Pw ^ swz));
            }
            #pragma unroll
            for (int tm = 0; tm < 4; ++tm)
                #pragma unroll
                for (int tn = 0; tn < 4; ++tn)
                    acc[tm][tn] = __builtin_amdgcn_mfma_f32_16x16x32_bf16(af[tm], wf[tn], acc[tm][tn], 0, 0, 0);
        }
        __syncthreads();
    }
    float bn[4];
    #pragma unroll
    for (int tn = 0; tn < 4; ++tn) {
        int n = n0 + wn + tn * 16 + lm;
        float b = 0.f;
        if (n < N) {
            if (bias) b = bias[n];
            if (bhh_fold) {                         // fold bhh for r,z gate columns
                int c = n < 384 ? n : n - 384;
                if (c < 256) b += bhh_fold[n];
            }
        }
        bn[tn] = b;
    }
    #pragma unroll
    for (int tm = 0; tm < 4; ++tm) {
        int mbase = m0 + wm + tm * 16 + kq * 4;   // C/D: col=lane&15, row=quad*4+reg (m89-verified)
        #pragma unroll
        for (int tn = 0; tn < 4; ++tn) {
            int n = n0 + wn + tn * 16 + lm;
            if (n < N) {
                #pragma unroll
                for (int i = 0; i < 4; ++i) {
                    int m = mbase + i;
                    if (m < M) {
                        float v = acc[tm][tn][i] + bn[tn];
                        if (NTC) __builtin_nontemporal_store(v, &C[(size_t)m * ldc + n]);
                        else     C[(size_t)m * ldc + n] = v;
                    }
                }
            }
        }
    }
}

// ---------------------------------------------------------------- GRU scan (in-register gates)
// 8 blocks = dir*4 + batch_quarter (16 rows). 512 thr = 8 waves.
// Wave w computes n-tiles {w, 8+w, 16+w} => lane (kq,lm) holds ghr/ghz/ghn for
// j = w*16+lm, batch rows kq*4+0..3 IN ACC REGISTERS after MFMA. Nonlinearity
// fully in-register; only h round-trips LDS (double-buffered -> ONE lds_barrier/step).
// Time loop unrolled x2: gi register sets A/B, each reloaded 2 steps ahead ->
// ~2 steps of latency cover; loads stay in flight across the lgkmcnt-only barrier.
// Gate MFMA chains split into two 2-deep halves (aX0+aX1) to halve dep latency.
__global__ __launch_bounds__(512) void gru_scan(const float* __restrict__ gi, int gi_tconst,
                                                const float* __restrict__ Whh,   // [2][384][128] fp32
                                                const float* __restrict__ bhh,   // [2][384] fp32
                                                ushort* __restrict__ y,          // [64][100][256] bf16 or null
                                                float* __restrict__ hf32,        // [64][512]
                                                ushort* __restrict__ hbf,        // [64][512] bf16 or null
                                                int hoff) {
    __shared__ __align__(16) ushort hbuf[2][16 * 136];   // bf16 h, [b][k] stride 136, double-buffered
    const int d = blockIdx.x >> 2, q = blockIdx.x & 3;
    const int tid = threadIdx.x;
    const int lane = tid & 63, w = tid >> 6;
    const int lm = lane & 15, kq = lane >> 4;
    const int j = w * 16 + lm;                            // this lane's hidden index

    for (int i = tid; i < 16 * 136; i += 512) hbuf[0][i] = 0;

    // B-frags for n-tiles {w, 8+w, 16+w}: lane's col = g*128 + j, k = kb*32 + kq*8 + idx.
    bf16x8 bfr[3][4];
    {
        const float* Wd = Whh + (size_t)d * 384 * 128;
        #pragma unroll
        for (int g = 0; g < 3; ++g)
            #pragma unroll
            for (int kb = 0; kb < 4; ++kb) {
                const float* p = &Wd[(size_t)(g * 128 + j) * 128 + kb * 32 + kq * 8];
                union { ushort u[8]; bf16x8 v; } t;
                #pragma unroll
                for (int e2 = 0; e2 < 8; ++e2) t.u[e2] = f2bf(p[e2]);
                bfr[g][kb] = t.v;
            }
    }
    const float bhn = bhh[d * 384 + 256 + j];
    const bool rev = (d == 1);

    float hreg[4] = {0.f, 0.f, 0.f, 0.f};
    float grA[4], gzA[4], gnA[4], grB[4], gzB[4], gnB[4];
    {   // prologue: load gi for first two steps
        int t0 = rev ? 99 : 0, t1 = rev ? 98 : 1;
        #pragma unroll
        for (int r = 0; r < 4; ++r) {
            int b = q * 16 + kq * 4 + r;
            const float* g0 = gi_tconst ? gi + (size_t)b * 768 + d * 384
                                        : gi + ((size_t)b * 100 + t0) * 768 + d * 384;
            grA[r] = g0[j]; gzA[r] = g0[128 + j]; gnA[r] = g0[256 + j];
            const float* g1 = gi_tconst ? gi + (size_t)b * 768 + d * 384
                                        : gi + ((size_t)b * 100 + t1) * 768 + d * 384;
            grB[r] = g1[j]; gzB[r] = g1[128 + j]; gnB[r] = g1[256 + j];
        }
    }
    lds_barrier();

    auto step = [&](int ti, int pb, float (&gr)[4], float (&gz)[4], float (&gn)[4]) {
        const int t = rev ? 99 - ti : ti;
        const ushort* hb = hbuf[pb];
        bf16x8 afr[4];
        #pragma unroll
        for (int kb = 0; kb < 4; ++kb)
            afr[kb] = *reinterpret_cast<const bf16x8*>(&hb[lm * 136 + kb * 32 + kq * 8]);
        // gh = h @ Whh.T : six 2-deep acc chains (r,z,n x lo/hi K-half)
        f32x4 aR0 = {0,0,0,0}, aZ0 = {0,0,0,0}, aN0 = {0,0,0,0};
        f32x4 aR1 = {0,0,0,0}, aZ1 = {0,0,0,0}, aN1 = {0,0,0,0};
        aR0 = __builtin_amdgcn_mfma_f32_16x16x32_bf16(afr[0], bfr[0][0], aR0, 0, 0, 0);
        aZ0 = __builtin_amdgcn_mfma_f32_16x16x32_bf16(afr[0], bfr[1][0], aZ0, 0, 0, 0);
        aN0 = __builtin_amdgcn_mfma_f32_16x16x32_bf16(afr[0], bfr[2][0], aN0, 0, 0, 0);
        aR1 = __builtin_amdgcn_mfma_f32_16x16x32_bf16(afr[2], bfr[0][2], aR1, 0, 0, 0);
        aZ1 = __builtin_amdgcn_mfma_f32_16x16x32_bf16(afr[2], bfr[1][2], aZ1, 0, 0, 0);
        aN1 = __builtin_amdgcn_mfma_f32_16x16x32_bf16(afr[2], bfr[2][2], aN1, 0, 0, 0);
        aR0 = __builtin_amdgcn_mfma_f32_16x16x32_bf16(afr[1], bfr[0][1], aR0, 0, 0, 0);
        aZ0 = __builtin_amdgcn_mfma_f32_16x16x32_bf16(afr[1], bfr[1][1], aZ0, 0, 0, 0);
        aN0 = __builtin_amdgcn_mfma_f32_16x16x32_bf16(afr[1], bfr[2][1], aN0, 0, 0, 0);
        aR1 = __builtin_amdgcn_mfma_f32_16x16x32_bf16(afr[3], bfr[0][3], aR1, 0, 0, 0);
        aZ1 = __builtin_amdgcn_mfma_f32_16x16x32_bf16(afr[3], bfr[1][3], aZ1, 0, 0, 0);
        aN1 = __builtin_amdgcn_mfma_f32_16x16x32_bf16(afr[3], bfr[2][3], aN1, 0, 0, 0);
        // nonlinearity, fully in-register (gi already has bih + bhh_{r,z} folded)
        ushort* hw = hbuf[pb ^ 1];
        #pragma unroll
        for (int r = 0; r < 4; ++r) {
            float rr = sigm(gr[r] + aR0[r] + aR1[r]);
            float zz = sigm(gz[r] + aZ0[r] + aZ1[r]);
            float nn = tanh_f(gn[r] + rr * (aN0[r] + aN1[r] + bhn));
            float h = nn + zz * (hreg[r] - nn);
            hreg[r] = h;
            hw[(kq * 4 + r) * 136 + j] = f2bf(h);
            if (y) {
                int b = q * 16 + kq * 4 + r;
                y[((size_t)b * 100 + t) * 256 + d * 128 + j] = f2bf(h);
            }
        }
        // reload THIS set for step ti+2 (consumed ~2 steps from issue)
        if (!gi_tconst && ti + 2 < 100) {
            int tn2 = rev ? 99 - (ti + 2) : ti + 2;
            #pragma unroll
            for (int r = 0; r < 4; ++r) {
                int b = q * 16 + kq * 4 + r;
                const float* g = gi + ((size_t)b * 100 + tn2) * 768 + d * 384;
                gr[r] = g[j]; gz[r] = g[128 + j]; gn[r] = g[256 + j];
            }
        }
        lds_barrier();   // LDS-only: gi loads / y stores stay in flight
    };

    #pragma unroll 1
    for (int ti = 0; ti < 100; ti += 2) {
        step(ti,     0, grA, gzA, gnA);
        step(ti + 1, 1, grB, gzB, gnB);
    }

    #pragma unroll
    for (int r = 0; r < 4; ++r) {
        int b = q * 16 + kq * 4 + r;
        int col = hoff + d * 128 + j;   // torch hidden layout: [l0f,l0b,l1f,l1b]
        hf32[(size_t)b * 512 + col] = hreg[r];
        if (hbf) hbf[(size_t)b * 512 + col] = f2bf(hreg[r]);
    }
}

// ---------------------------------------------------------------- fc head: out = [enc_h, dec_h] @ fc_W.T + fc_b
__global__ __launch_bounds__(256) void fc_out(const float* __restrict__ ench,
                                              const float* __restrict__ dech,
                                              const float* __restrict__ W,
                                              const float* __restrict__ bias,
                                              float* __restrict__ out) {
    __shared__ float v[1024];
    int b = blockIdx.x, tid = threadIdx.x;
    for (int i = tid; i < 1024; i += 256)
        v[i] = (i < 512) ? ench[b * 512 + i] : dech[b * 512 + i - 512];
    __syncthreads();
    int wave = tid >> 6, lane = tid & 63;
    for (int c = wave; c < 20; c += 4) {
        float s = 0.f;
        for (int k = lane; k < 1024; k += 64) s += v[k] * W[c * 1024 + k];
        #pragma unroll
        for (int off = 32; off >= 1; off >>= 1) s += __shfl_xor(s, off, 64);
        if (lane == 0) out[b * 20 + c] = s + bias[c];
    }
}

// ---------------------------------------------------------------- launch
extern "C" void kernel_launch(void* const* d_in, const int* in_sizes, int n_in,
                              void* d_out, int out_size, void* d_ws, size_t ws_size,
                              hipStream_t stream) {
    const int*   x     = (const int*)  d_in[0];
    const float* emb   = (const float*)d_in[1];
    const float* eWih0 = (const float*)d_in[2];
    const float* eWhh0 = (const float*)d_in[3];
    const float* ebih0 = (const float*)d_in[4];
    const float* ebhh0 = (const float*)d_in[5];
    const float* eWih1 = (const float*)d_in[6];
    const float* eWhh1 = (const float*)d_in[7];
    const float* ebih1 = (const float*)d_in[8];
    const float* ebhh1 = (const float*)d_in[9];
    const float* dWih0 = (const float*)d_in[10];
    const float* dWhh0 = (const float*)d_in[11];
    const float* dbih0 = (const float*)d_in[12];
    const float* dbhh0 = (const float*)d_in[13];
    const float* dWih1 = (const float*)d_in[14];
    const float* dWhh1 = (const float*)d_in[15];
    const float* dbih1 = (const float*)d_in[16];
    const float* dbhh1 = (const float*)d_in[17];
    const float* fcW   = (const float*)d_in[18];
    const float* fcb   = (const float*)d_in[19];
    const float* recW  = (const float*)d_in[20];
    const float* recb  = (const float*)d_in[21];

    char* ws = (char*)d_ws;
    size_t off = 0;
    auto alloc = [&](size_t bytes) {
        char* p = ws + off;
        off = (off + bytes + 255) & ~(size_t)255;
        return p;
    };
    float*  gi    = (float*) alloc((size_t)6400 * 768 * 4);   // gate inputs (fp32, reused 3x)
    ushort* yA    = (ushort*)alloc((size_t)6400 * 256 * 2);   // enc l0 / dec l0 output seq (bf16)
    ushort* y1d   = (ushort*)alloc((size_t)6400 * 256 * 2);   // dec l1 output = rec_seq (bf16)
    ushort* wbuf  = (ushort*)alloc((size_t)3444736 * 2);      // bf16: eWih0|eWih1|dWih0|dWih1|recW
    float*  digi  = (float*) alloc((size_t)64 * 768 * 4);     // dec l0 time-constant gi
    float*  enchf = (float*) alloc((size_t)64 * 512 * 4);
    ushort* enchb = (ushort*)alloc((size_t)64 * 512 * 2);
    float*  dechf = (float*) alloc((size_t)64 * 512 * 4);
    alloc(65536);   // tail slack: OOB tile reads (N/M tails) stay inside ws
    (void)ws_size;

    ushort* w_e0  = wbuf;
    ushort* w_e1  = wbuf + 98304;
    ushort* w_d0  = wbuf + 294912;
    ushort* w_d1  = wbuf + 688128;
    ushort* w_rec = wbuf + 884736;

    float* out_fc  = (float*)d_out;              // [64][20]
    float* out_rec = (float*)d_out + 1280;       // [64][100][10000]

    // one-shot weight conversion (all Wih + recW -> bf16), 430592 threads exactly
    cvt_all<<<1682, 256, 0, stream>>>(eWih0, eWih1, dWih0, dWih1, recW, wbuf);

    // encoder layer 0: A gathered from emb via x (bhh r,z folded into gi)
    gemm_bt<true, false, false><<<dim3(6, 50), 256, 0, stream>>>(nullptr, 128, w_e0, 128, ebih0, ebhh0,
                                                                 gi, 768, 6400, 768, 128, emb, x);
    gru_scan<<<8, 512, 0, stream>>>(gi, 0, eWhh0, ebhh0, yA, enchf, enchb, 0);
    // encoder layer 1 (only final h needed); A = yA (3.3MB, L2-resident) -> direct
    gemm_bt<false, true, false><<<dim3(6, 50), 256, 0, stream>>>(yA, 256, w_e1, 256, ebih1, ebhh1,
                                                                 gi, 768, 6400, 768, 256, nullptr, nullptr);
    gru_scan<<<8, 512, 0, stream>>>(gi, 0, eWhh1, ebhh1, nullptr, enchf, enchb, 256);
    // decoder layer 0: broadcast enc_h -> gi constant over t (M=64 tail -> staged path)
    gemm_bt<false, false, false><<<dim3(6, 1), 256, 0, stream>>>(enchb, 512, w_d0, 512, dbih0, dbhh0,
                                                                 digi, 768, 64, 768, 512, nullptr, nullptr);
    gru_scan<<<8, 512, 0, stream>>>(digi, 1, dWhh0, dbhh0, yA, dechf, nullptr, 0);
    // decoder layer 1; A = yA direct
    gemm_bt<false, true, false><<<dim3(6, 50), 256, 0, stream>>>(yA, 256, w_d1, 256, dbih1, dbhh1,
                                                                 gi, 768, 6400, 768, 256, nullptr, nullptr);
    gru_scan<<<8, 512, 0, stream>>>(gi, 0, dWhh1, dbhh1, y1d, dechf, nullptr, 256);
    // reconstruction GEMM (A = y1d direct; nontemporal C stores)
    gemm_bt<false, true, true><<<dim3(79, 50), 256, 0, stream>>>(y1d, 256, w_rec, 256, recb, nullptr,
                                                                 out_rec, 10000, 6400, 10000, 256, nullptr, nullptr);
    // fc head
    fc_out<<<64, 256, 0, stream>>>(enchf, dechf, fcW, fcb, out_fc);
}

// Round 6
// 1001.158 us; speedup vs baseline: 1.0546x; 1.0546x over previous
//
#include <hip/hip_runtime.h>
#include <hip/hip_bf16.h>

// FSNet: embed -> bi-GRU(2) encoder -> broadcast -> bi-GRU(2) decoder
//        -> fc head (64x20) + reconstruction GEMM (64x100x10000)
// R5 changes vs R4 (1055.8 us; R3 was 1004.6):
//  - REVERT ADIRECT (R4 post-mortem: per-wave A loads = 2x redundant + scattered;
//    FETCH 131MB vs 8.4MB ideal, rec GEMM 167us). All GEMMs: global_load_lds staging.
//  - rec GEMM: bijective XCD swizzle (m204 formula; nwg=3950 not %8) -> each XCD
//    owns contiguous runs of n-blocks sharing the A panel (L2-resident).
//  - scan unroll-2 from R4 kept unchanged (R5 vs R3 isolates it).
// Numerics identical to R4.

typedef __bf16 bf16x8 __attribute__((ext_vector_type(8)));
typedef float f32x4 __attribute__((ext_vector_type(4)));

__device__ __forceinline__ ushort f2bf(float f) {
    __hip_bfloat16 h = __float2bfloat16(f);   // RNE
    return *reinterpret_cast<ushort*>(&h);
}
__device__ __forceinline__ float sigm(float x) {
    return 1.f / (1.f + __expf(-x));
}
__device__ __forceinline__ float tanh_f(float x) {
    x = fminf(fmaxf(x, -15.f), 15.f);
    float e = __expf(2.f * x);
    return (e - 1.f) / (e + 1.f);
}
// LDS-only barrier: orders ds_write -> ds_read without draining vmcnt.
__device__ __forceinline__ void lds_barrier() {
    asm volatile("s_waitcnt lgkmcnt(0)" ::: "memory");
    __builtin_amdgcn_s_barrier();
}
// async global->LDS, 16B per lane; lds base is wave-uniform, HW adds lane*16.
__device__ __forceinline__ void gload16(const void* g, void* l) {
    __builtin_amdgcn_global_load_lds(
        (const __attribute__((address_space(1))) unsigned int*)g,
        (__attribute__((address_space(3))) unsigned int*)l, 16, 0, 0);
}

// ---------------------------------------------------------------- fp32 -> bf16, 5 segments, one dispatch
// dst layout (elements): [eWih0:98304][eWih1:196608][dWih0:393216][dWih1:196608][recW:2560000]
__global__ __launch_bounds__(256) void cvt_all(const float* __restrict__ s0,
                                               const float* __restrict__ s1,
                                               const float* __restrict__ s2,
                                               const float* __restrict__ s3,
                                               const float* __restrict__ s4,
                                               ushort* __restrict__ dst) {
    int i = blockIdx.x * 256 + threadIdx.x;         // 430592 threads exactly
    size_t e = (size_t)i * 8;
    const float* s; size_t off;
    if      (e < 98304)  { s = s0; off = e; }
    else if (e < 294912) { s = s1; off = e - 98304; }
    else if (e < 688128) { s = s2; off = e - 294912; }
    else if (e < 884736) { s = s3; off = e - 688128; }
    else                 { s = s4; off = e - 884736; }
    const float* p = s + off;
    ushort4 lo, hi;
    lo.x = f2bf(p[0]); lo.y = f2bf(p[1]); lo.z = f2bf(p[2]); lo.w = f2bf(p[3]);
    hi.x = f2bf(p[4]); hi.y = f2bf(p[5]); hi.z = f2bf(p[6]); hi.w = f2bf(p[7]);
    ushort* d = dst + e;
    *reinterpret_cast<ushort4*>(d)     = lo;
    *reinterpret_cast<ushort4*>(d + 4) = hi;
}

// ---------------------------------------------------------------- GEMM C = A @ W.T + bias (fp32 out)
// A: [M][K] bf16 (AGATHER: emb rows via x, reg-staged). W: [N][K] bf16, gload_lds.
// 128x128 tile, 4 waves, mfma 16x16x32 bf16. LDS linear [128][64]u16 with
// byte ^= ((row&7)<<4) swizzle (write via pre-swizzled gload source; read swizzled).
// XSWZ: bijective XCD-contiguous block remap (m204) for A-panel L2 locality.
// OOB tile rows (N tail, M=64 case) read garbage from within ws -- never stored.
// bhh_fold (optional, N=768 GRU case): adds bhh[n] for gate cols (n%384)<256 (r,z biases).
template <bool AGATHER, bool NTC, bool XSWZ>
__global__ __launch_bounds__(256) void gemm_bt(const ushort* __restrict__ A, int lda,
                                               const ushort* __restrict__ W, int ldw,
                                               const float* __restrict__ bias,
                                               const float* __restrict__ bhh_fold,
                                               float* __restrict__ C, int ldc,
                                               int M, int N, int K,
                                               const float* __restrict__ embp,
                                               const int* __restrict__ xidx) {
    __shared__ __align__(16) ushort As[128 * 64];   // linear, 16KB
    __shared__ __align__(16) ushort Ws[128 * 64];
    const int tid = threadIdx.x;
    const int lane = tid & 63, wave = tid >> 6;
    int bx = blockIdx.x, by = blockIdx.y;
    if (XSWZ) {
        // bijective XCD swizzle (m204): consecutive HW-dispatch ids round-robin
        // XCDs; give each XCD a contiguous range of logical blocks.
        int nx = gridDim.x;
        int nwg = nx * gridDim.y;
        int bid = by * nx + bx;
        int q = nwg >> 3, r = nwg & 7;
        int xcd = bid & 7, loc = bid >> 3;
        int swz = (xcd < r ? xcd * (q + 1) : r * (q + 1) + (xcd - r) * q) + loc;
        bx = swz % nx;
        by = swz / nx;
    }
    const int n0 = bx * 128, m0 = by * 128;
    const int wm = (wave >> 1) * 64, wn = (wave & 1) * 64;
    const int lm = lane & 15, kq = lane >> 4;
    const int swz = (lm & 7) << 4;                  // read-side XOR (row&7 == lm&7)
    f32x4 acc[4][4] = {};

    for (int kb = 0; kb < K; kb += 64) {
        if (AGATHER) {
            // A rows gathered from emb via x (fp32 -> bf16), swizzled ds_write.
            #pragma unroll
            for (int it = 0; it < 8; ++it) {        // 2048 float4 chunks
                int chunk = it * 256 + tid;
                int row = chunk >> 4, kc = chunk & 15;
                int xi = xidx[m0 + row];
                xi = xi > 9999 ? 9999 : (xi < 0 ? 0 : xi);
                float4 a4 = *reinterpret_cast<const float4*>(&embp[(size_t)xi * 128 + kb + kc * 4]);
                ushort4 b4;
                b4.x = f2bf(a4.x); b4.y = f2bf(a4.y); b4.z = f2bf(a4.z); b4.w = f2bf(a4.w);
                int sb = (row * 128 + kc * 8) ^ ((row & 7) << 4);
                *reinterpret_cast<ushort4*>((char*)As + sb) = b4;
            }
        } else {
            #pragma unroll
            for (int seg = 0; seg < 4; ++seg) {     // 4KB per wave, 1KB per call
                int chunk = (wave * 4 + seg) * 64 + lane;   // 0..1023
                int L  = chunk * 16;                         // linear LDS byte
                int Ls = L ^ (((L >> 7) & 7) << 4);          // logical byte stored here
                int row = Ls >> 7, colb = Ls & 127;
                gload16(&A[(size_t)(m0 + row) * lda + kb + (colb >> 1)],
                        (char*)As + (wave * 4 + seg) * 1024);
            }
        }
        #pragma unroll
        for (int seg = 0; seg < 4; ++seg) {         // W bf16 via gload_lds
            int chunk = (wave * 4 + seg) * 64 + lane;
            int L  = chunk * 16;
            int Ls = L ^ (((L >> 7) & 7) << 4);
            int row = Ls >> 7, colb = Ls & 127;
            gload16(&W[(size_t)(n0 + row) * ldw + kb + (colb >> 1)],
                    (char*)Ws + (wave * 4 + seg) * 1024);
        }
        __syncthreads();                            // drains vmcnt (gload) + lgkmcnt
        #pragma unroll
        for (int k2 = 0; k2 < 2; ++k2) {
            bf16x8 af[4], wf[4];
            #pragma unroll
            for (int tt = 0; tt < 4; ++tt) {
                int Pa = (wm + tt * 16 + lm) * 128 + k2 * 64 + kq * 16;
                int Pw = (wn + tt * 16 + lm) * 128 + k2 * 64 + kq * 16;
                af[tt] = *reinterpret_cast<const bf16x8*>((const char*)As + (Pa ^ swz));
                wf[tt] = *reinterpret_cast<const bf16x8*>((const char*)Ws + (Pw ^ swz));
            }
            #pragma unroll
            for (int tm = 0; tm < 4; ++tm)
                #pragma unroll
                for (int tn = 0; tn < 4; ++tn)
                    acc[tm][tn] = __builtin_amdgcn_mfma_f32_16x16x32_bf16(af[tm], wf[tn], acc[tm][tn], 0, 0, 0);
        }
        __syncthreads();
    }
    float bn[4];
    #pragma unroll
    for (int tn = 0; tn < 4; ++tn) {
        int n = n0 + wn + tn * 16 + lm;
        float b = 0.f;
        if (n < N) {
            if (bias) b = bias[n];
            if (bhh_fold) {                         // fold bhh for r,z gate columns
                int c = n < 384 ? n : n - 384;
                if (c < 256) b += bhh_fold[n];
            }
        }
        bn[tn] = b;
    }
    #pragma unroll
    for (int tm = 0; tm < 4; ++tm) {
        int mbase = m0 + wm + tm * 16 + kq * 4;   // C/D: col=lane&15, row=quad*4+reg (m89-verified)
        #pragma unroll
        for (int tn = 0; tn < 4; ++tn) {
            int n = n0 + wn + tn * 16 + lm;
            if (n < N) {
                #pragma unroll
                for (int i = 0; i < 4; ++i) {
                    int m = mbase + i;
                    if (m < M) {
                        float v = acc[tm][tn][i] + bn[tn];
                        if (NTC) __builtin_nontemporal_store(v, &C[(size_t)m * ldc + n]);
                        else     C[(size_t)m * ldc + n] = v;
                    }
                }
            }
        }
    }
}

// ---------------------------------------------------------------- GRU scan (in-register gates)
// 8 blocks = dir*4 + batch_quarter (16 rows). 512 thr = 8 waves.
// Wave w computes n-tiles {w, 8+w, 16+w} => lane (kq,lm) holds ghr/ghz/ghn for
// j = w*16+lm, batch rows kq*4+0..3 IN ACC REGISTERS after MFMA. Nonlinearity
// fully in-register; only h round-trips LDS (double-buffered -> ONE lds_barrier/step).
// Time loop unrolled x2: gi register sets A/B, each reloaded 2 steps ahead ->
// ~2 steps of latency cover; loads stay in flight across the lgkmcnt-only barrier.
// Gate MFMA chains split into two 2-deep halves (aX0+aX1) to halve dep latency.
__global__ __launch_bounds__(512) void gru_scan(const float* __restrict__ gi, int gi_tconst,
                                                const float* __restrict__ Whh,   // [2][384][128] fp32
                                                const float* __restrict__ bhh,   // [2][384] fp32
                                                ushort* __restrict__ y,          // [64][100][256] bf16 or null
                                                float* __restrict__ hf32,        // [64][512]
                                                ushort* __restrict__ hbf,        // [64][512] bf16 or null
                                                int hoff) {
    __shared__ __align__(16) ushort hbuf[2][16 * 136];   // bf16 h, [b][k] stride 136, double-buffered
    const int d = blockIdx.x >> 2, q = blockIdx.x & 3;
    const int tid = threadIdx.x;
    const int lane = tid & 63, w = tid >> 6;
    const int lm = lane & 15, kq = lane >> 4;
    const int j = w * 16 + lm;                            // this lane's hidden index

    for (int i = tid; i < 16 * 136; i += 512) hbuf[0][i] = 0;

    // B-frags for n-tiles {w, 8+w, 16+w}: lane's col = g*128 + j, k = kb*32 + kq*8 + idx.
    bf16x8 bfr[3][4];
    {
        const float* Wd = Whh + (size_t)d * 384 * 128;
        #pragma unroll
        for (int g = 0; g < 3; ++g)
            #pragma unroll
            for (int kb = 0; kb < 4; ++kb) {
                const float* p = &Wd[(size_t)(g * 128 + j) * 128 + kb * 32 + kq * 8];
                union { ushort u[8]; bf16x8 v; } t;
                #pragma unroll
                for (int e2 = 0; e2 < 8; ++e2) t.u[e2] = f2bf(p[e2]);
                bfr[g][kb] = t.v;
            }
    }
    const float bhn = bhh[d * 384 + 256 + j];
    const bool rev = (d == 1);

    float hreg[4] = {0.f, 0.f, 0.f, 0.f};
    float grA[4], gzA[4], gnA[4], grB[4], gzB[4], gnB[4];
    {   // prologue: load gi for first two steps
        int t0 = rev ? 99 : 0, t1 = rev ? 98 : 1;
        #pragma unroll
        for (int r = 0; r < 4; ++r) {
            int b = q * 16 + kq * 4 + r;
            const float* g0 = gi_tconst ? gi + (size_t)b * 768 + d * 384
                                        : gi + ((size_t)b * 100 + t0) * 768 + d * 384;
            grA[r] = g0[j]; gzA[r] = g0[128 + j]; gnA[r] = g0[256 + j];
            const float* g1 = gi_tconst ? gi + (size_t)b * 768 + d * 384
                                        : gi + ((size_t)b * 100 + t1) * 768 + d * 384;
            grB[r] = g1[j]; gzB[r] = g1[128 + j]; gnB[r] = g1[256 + j];
        }
    }
    lds_barrier();

    auto step = [&](int ti, int pb, float (&gr)[4], float (&gz)[4], float (&gn)[4]) {
        const int t = rev ? 99 - ti : ti;
        const ushort* hb = hbuf[pb];
        bf16x8 afr[4];
        #pragma unroll
        for (int kb = 0; kb < 4; ++kb)
            afr[kb] = *reinterpret_cast<const bf16x8*>(&hb[lm * 136 + kb * 32 + kq * 8]);
        // gh = h @ Whh.T : six 2-deep acc chains (r,z,n x lo/hi K-half)
        f32x4 aR0 = {0,0,0,0}, aZ0 = {0,0,0,0}, aN0 = {0,0,0,0};
        f32x4 aR1 = {0,0,0,0}, aZ1 = {0,0,0,0}, aN1 = {0,0,0,0};
        aR0 = __builtin_amdgcn_mfma_f32_16x16x32_bf16(afr[0], bfr[0][0], aR0, 0, 0, 0);
        aZ0 = __builtin_amdgcn_mfma_f32_16x16x32_bf16(afr[0], bfr[1][0], aZ0, 0, 0, 0);
        aN0 = __builtin_amdgcn_mfma_f32_16x16x32_bf16(afr[0], bfr[2][0], aN0, 0, 0, 0);
        aR1 = __builtin_amdgcn_mfma_f32_16x16x32_bf16(afr[2], bfr[0][2], aR1, 0, 0, 0);
        aZ1 = __builtin_amdgcn_mfma_f32_16x16x32_bf16(afr[2], bfr[1][2], aZ1, 0, 0, 0);
        aN1 = __builtin_amdgcn_mfma_f32_16x16x32_bf16(afr[2], bfr[2][2], aN1, 0, 0, 0);
        aR0 = __builtin_amdgcn_mfma_f32_16x16x32_bf16(afr[1], bfr[0][1], aR0, 0, 0, 0);
        aZ0 = __builtin_amdgcn_mfma_f32_16x16x32_bf16(afr[1], bfr[1][1], aZ0, 0, 0, 0);
        aN0 = __builtin_amdgcn_mfma_f32_16x16x32_bf16(afr[1], bfr[2][1], aN0, 0, 0, 0);
        aR1 = __builtin_amdgcn_mfma_f32_16x16x32_bf16(afr[3], bfr[0][3], aR1, 0, 0, 0);
        aZ1 = __builtin_amdgcn_mfma_f32_16x16x32_bf16(afr[3], bfr[1][3], aZ1, 0, 0, 0);
        aN1 = __builtin_amdgcn_mfma_f32_16x16x32_bf16(afr[3], bfr[2][3], aN1, 0, 0, 0);
        // nonlinearity, fully in-register (gi already has bih + bhh_{r,z} folded)
        ushort* hw = hbuf[pb ^ 1];
        #pragma unroll
        for (int r = 0; r < 4; ++r) {
            float rr = sigm(gr[r] + aR0[r] + aR1[r]);
            float zz = sigm(gz[r] + aZ0[r] + aZ1[r]);
            float nn = tanh_f(gn[r] + rr * (aN0[r] + aN1[r] + bhn));
            float h = nn + zz * (hreg[r] - nn);
            hreg[r] = h;
            hw[(kq * 4 + r) * 136 + j] = f2bf(h);
            if (y) {
                int b = q * 16 + kq * 4 + r;
                y[((size_t)b * 100 + t) * 256 + d * 128 + j] = f2bf(h);
            }
        }
        // reload THIS set for step ti+2 (consumed ~2 steps from issue)
        if (!gi_tconst && ti + 2 < 100) {
            int tn2 = rev ? 99 - (ti + 2) : ti + 2;
            #pragma unroll
            for (int r = 0; r < 4; ++r) {
                int b = q * 16 + kq * 4 + r;
                const float* g = gi + ((size_t)b * 100 + tn2) * 768 + d * 384;
                gr[r] = g[j]; gz[r] = g[128 + j]; gn[r] = g[256 + j];
            }
        }
        lds_barrier();   // LDS-only: gi loads / y stores stay in flight
    };

    #pragma unroll 1
    for (int ti = 0; ti < 100; ti += 2) {
        step(ti,     0, grA, gzA, gnA);
        step(ti + 1, 1, grB, gzB, gnB);
    }

    #pragma unroll
    for (int r = 0; r < 4; ++r) {
        int b = q * 16 + kq * 4 + r;
        int col = hoff + d * 128 + j;   // torch hidden layout: [l0f,l0b,l1f,l1b]
        hf32[(size_t)b * 512 + col] = hreg[r];
        if (hbf) hbf[(size_t)b * 512 + col] = f2bf(hreg[r]);
    }
}

// ---------------------------------------------------------------- fc head: out = [enc_h, dec_h] @ fc_W.T + fc_b
__global__ __launch_bounds__(256) void fc_out(const float* __restrict__ ench,
                                              const float* __restrict__ dech,
                                              const float* __restrict__ W,
                                              const float* __restrict__ bias,
                                              float* __restrict__ out) {
    __shared__ float v[1024];
    int b = blockIdx.x, tid = threadIdx.x;
    for (int i = tid; i < 1024; i += 256)
        v[i] = (i < 512) ? ench[b * 512 + i] : dech[b * 512 + i - 512];
    __syncthreads();
    int wave = tid >> 6, lane = tid & 63;
    for (int c = wave; c < 20; c += 4) {
        float s = 0.f;
        for (int k = lane; k < 1024; k += 64) s += v[k] * W[c * 1024 + k];
        #pragma unroll
        for (int off = 32; off >= 1; off >>= 1) s += __shfl_xor(s, off, 64);
        if (lane == 0) out[b * 20 + c] = s + bias[c];
    }
}

// ---------------------------------------------------------------- launch
extern "C" void kernel_launch(void* const* d_in, const int* in_sizes, int n_in,
                              void* d_out, int out_size, void* d_ws, size_t ws_size,
                              hipStream_t stream) {
    const int*   x     = (const int*)  d_in[0];
    const float* emb   = (const float*)d_in[1];
    const float* eWih0 = (const float*)d_in[2];
    const float* eWhh0 = (const float*)d_in[3];
    const float* ebih0 = (const float*)d_in[4];
    const float* ebhh0 = (const float*)d_in[5];
    const float* eWih1 = (const float*)d_in[6];
    const float* eWhh1 = (const float*)d_in[7];
    const float* ebih1 = (const float*)d_in[8];
    const float* ebhh1 = (const float*)d_in[9];
    const float* dWih0 = (const float*)d_in[10];
    const float* dWhh0 = (const float*)d_in[11];
    const float* dbih0 = (const float*)d_in[12];
    const float* dbhh0 = (const float*)d_in[13];
    const float* dWih1 = (const float*)d_in[14];
    const float* dWhh1 = (const float*)d_in[15];
    const float* dbih1 = (const float*)d_in[16];
    const float* dbhh1 = (const float*)d_in[17];
    const float* fcW   = (const float*)d_in[18];
    const float* fcb   = (const float*)d_in[19];
    const float* recW  = (const float*)d_in[20];
    const float* recb  = (const float*)d_in[21];

    char* ws = (char*)d_ws;
    size_t off = 0;
    auto alloc = [&](size_t bytes) {
        char* p = ws + off;
        off = (off + bytes + 255) & ~(size_t)255;
        return p;
    };
    float*  gi    = (float*) alloc((size_t)6400 * 768 * 4);   // gate inputs (fp32, reused 3x)
    ushort* yA    = (ushort*)alloc((size_t)6400 * 256 * 2);   // enc l0 / dec l0 output seq (bf16)
    ushort* y1d   = (ushort*)alloc((size_t)6400 * 256 * 2);   // dec l1 output = rec_seq (bf16)
    ushort* wbuf  = (ushort*)alloc((size_t)3444736 * 2);      // bf16: eWih0|eWih1|dWih0|dWih1|recW
    float*  digi  = (float*) alloc((size_t)64 * 768 * 4);     // dec l0 time-constant gi
    float*  enchf = (float*) alloc((size_t)64 * 512 * 4);
    ushort* enchb = (ushort*)alloc((size_t)64 * 512 * 2);
    float*  dechf = (float*) alloc((size_t)64 * 512 * 4);
    alloc(65536);   // tail slack: OOB tile reads (N/M tails) stay inside ws
    (void)ws_size;

    ushort* w_e0  = wbuf;
    ushort* w_e1  = wbuf + 98304;
    ushort* w_d0  = wbuf + 294912;
    ushort* w_d1  = wbuf + 688128;
    ushort* w_rec = wbuf + 884736;

    float* out_fc  = (float*)d_out;              // [64][20]
    float* out_rec = (float*)d_out + 1280;       // [64][100][10000]

    // one-shot weight conversion (all Wih + recW -> bf16), 430592 threads exactly
    cvt_all<<<1682, 256, 0, stream>>>(eWih0, eWih1, dWih0, dWih1, recW, wbuf);

    // encoder layer 0: A gathered from emb via x (bhh r,z folded into gi)
    gemm_bt<true, false, false><<<dim3(6, 50), 256, 0, stream>>>(nullptr, 128, w_e0, 128, ebih0, ebhh0,
                                                                 gi, 768, 6400, 768, 128, emb, x);
    gru_scan<<<8, 512, 0, stream>>>(gi, 0, eWhh0, ebhh0, yA, enchf, enchb, 0);
    // encoder layer 1 (only final h needed)
    gemm_bt<false, false, false><<<dim3(6, 50), 256, 0, stream>>>(yA, 256, w_e1, 256, ebih1, ebhh1,
                                                                  gi, 768, 6400, 768, 256, nullptr, nullptr);
    gru_scan<<<8, 512, 0, stream>>>(gi, 0, eWhh1, ebhh1, nullptr, enchf, enchb, 256);
    // decoder layer 0: broadcast enc_h -> gi constant over t
    gemm_bt<false, false, false><<<dim3(6, 1), 256, 0, stream>>>(enchb, 512, w_d0, 512, dbih0, dbhh0,
                                                                 digi, 768, 64, 768, 512, nullptr, nullptr);
    gru_scan<<<8, 512, 0, stream>>>(digi, 1, dWhh0, dbhh0, yA, dechf, nullptr, 0);
    // decoder layer 1
    gemm_bt<false, false, false><<<dim3(6, 50), 256, 0, stream>>>(yA, 256, w_d1, 256, dbih1, dbhh1,
                                                                  gi, 768, 6400, 768, 256, nullptr, nullptr);
    gru_scan<<<8, 512, 0, stream>>>(gi, 0, dWhh1, dbhh1, y1d, dechf, nullptr, 256);
    // reconstruction GEMM (gload_lds staging; XCD-swizzled blocks; NT C stores)
    gemm_bt<false, true, true><<<dim3(79, 50), 256, 0, stream>>>(y1d, 256, w_rec, 256, recb, nullptr,
                                                                 out_rec, 10000, 6400, 10000, 256, nullptr, nullptr);
    // fc head
    fc_out<<<64, 256, 0, stream>>>(enchf, dechf, fcW, fcb, out_fc);
}

// Round 7
// 989.382 us; speedup vs baseline: 1.0672x; 1.0119x over previous
//
#include <hip/hip_runtime.h>
#include <hip/hip_bf16.h>

// FSNet: embed -> bi-GRU(2) encoder -> broadcast -> bi-GRU(2) decoder
//        -> fc head (64x20) + reconstruction GEMM (64x100x10000)
// R7 changes vs R6 (1001.2 us):
//  - cvt_all also converts the four Whh matrices -> scans load B-frags as 12
//    bf16x8 vector loads instead of 96 scalar fp32 loads + cvt (8-block serial
//    prologue latency).
//  - XSWZ enabled on the three 300-block gi GEMMs (bijective m204 swizzle).
// Numerics bitwise-identical to R6 (same f2bf RNE, same MFMA order) ->
// absmax canary must stay 0.001953125.

typedef __bf16 bf16x8 __attribute__((ext_vector_type(8)));
typedef float f32x4 __attribute__((ext_vector_type(4)));

__device__ __forceinline__ ushort f2bf(float f) {
    __hip_bfloat16 h = __float2bfloat16(f);   // RNE
    return *reinterpret_cast<ushort*>(&h);
}
__device__ __forceinline__ float sigm(float x) {
    return 1.f / (1.f + __expf(-x));
}
__device__ __forceinline__ float tanh_f(float x) {
    x = fminf(fmaxf(x, -15.f), 15.f);
    float e = __expf(2.f * x);
    return (e - 1.f) / (e + 1.f);
}
// LDS-only barrier: orders ds_write -> ds_read without draining vmcnt.
__device__ __forceinline__ void lds_barrier() {
    asm volatile("s_waitcnt lgkmcnt(0)" ::: "memory");
    __builtin_amdgcn_s_barrier();
}
// async global->LDS, 16B per lane; lds base is wave-uniform, HW adds lane*16.
__device__ __forceinline__ void gload16(const void* g, void* l) {
    __builtin_amdgcn_global_load_lds(
        (const __attribute__((address_space(1))) unsigned int*)g,
        (__attribute__((address_space(3))) unsigned int*)l, 16, 0, 0);
}

// ---------------------------------------------------------------- fp32 -> bf16, 9 segments, one dispatch
// dst layout (elements):
//  [eWih0:98304][eWih1:196608][dWih0:393216][dWih1:196608][recW:2560000]
//  [eWhh0:98304][eWhh1:98304][dWhh0:98304][dWhh1:98304]   total 3837952
__global__ __launch_bounds__(256) void cvt_all(const float* __restrict__ s0,
                                               const float* __restrict__ s1,
                                               const float* __restrict__ s2,
                                               const float* __restrict__ s3,
                                               const float* __restrict__ s4,
                                               const float* __restrict__ s5,
                                               const float* __restrict__ s6,
                                               const float* __restrict__ s7,
                                               const float* __restrict__ s8,
                                               ushort* __restrict__ dst) {
    int i = blockIdx.x * 256 + threadIdx.x;         // 479744 threads exactly
    size_t e = (size_t)i * 8;
    const float* s; size_t off;
    if      (e < 98304)   { s = s0; off = e; }
    else if (e < 294912)  { s = s1; off = e - 98304; }
    else if (e < 688128)  { s = s2; off = e - 294912; }
    else if (e < 884736)  { s = s3; off = e - 688128; }
    else if (e < 3444736) { s = s4; off = e - 884736; }
    else if (e < 3543040) { s = s5; off = e - 3444736; }
    else if (e < 3641344) { s = s6; off = e - 3543040; }
    else if (e < 3739648) { s = s7; off = e - 3641344; }
    else                  { s = s8; off = e - 3739648; }
    const float* p = s + off;
    ushort4 lo, hi;
    lo.x = f2bf(p[0]); lo.y = f2bf(p[1]); lo.z = f2bf(p[2]); lo.w = f2bf(p[3]);
    hi.x = f2bf(p[4]); hi.y = f2bf(p[5]); hi.z = f2bf(p[6]); hi.w = f2bf(p[7]);
    ushort* d = dst + e;
    *reinterpret_cast<ushort4*>(d)     = lo;
    *reinterpret_cast<ushort4*>(d + 4) = hi;
}

// ---------------------------------------------------------------- GEMM C = A @ W.T + bias (fp32 out)
// A: [M][K] bf16 (AGATHER: emb rows via x, reg-staged). W: [N][K] bf16, gload_lds.
// 128x128 tile, 4 waves, mfma 16x16x32 bf16. LDS linear [128][64]u16 with
// byte ^= ((row&7)<<4) swizzle (write via pre-swizzled gload source; read swizzled).
// XSWZ: bijective XCD-contiguous block remap (m204) for A/W L2 locality.
// OOB tile rows (N tail, M=64 case) read garbage from within ws -- never stored.
// bhh_fold (optional, N=768 GRU case): adds bhh[n] for gate cols (n%384)<256 (r,z biases).
template <bool AGATHER, bool NTC, bool XSWZ>
__global__ __launch_bounds__(256) void gemm_bt(const ushort* __restrict__ A, int lda,
                                               const ushort* __restrict__ W, int ldw,
                                               const float* __restrict__ bias,
                                               const float* __restrict__ bhh_fold,
                                               float* __restrict__ C, int ldc,
                                               int M, int N, int K,
                                               const float* __restrict__ embp,
                                               const int* __restrict__ xidx) {
    __shared__ __align__(16) ushort As[128 * 64];   // linear, 16KB
    __shared__ __align__(16) ushort Ws[128 * 64];
    const int tid = threadIdx.x;
    const int lane = tid & 63, wave = tid >> 6;
    int bx = blockIdx.x, by = blockIdx.y;
    if (XSWZ) {
        // bijective XCD swizzle (m204): consecutive HW-dispatch ids round-robin
        // XCDs; give each XCD a contiguous range of logical blocks.
        int nx = gridDim.x;
        int nwg = nx * gridDim.y;
        int bid = by * nx + bx;
        int q = nwg >> 3, r = nwg & 7;
        int xcd = bid & 7, loc = bid >> 3;
        int swz = (xcd < r ? xcd * (q + 1) : r * (q + 1) + (xcd - r) * q) + loc;
        bx = swz % nx;
        by = swz / nx;
    }
    const int n0 = bx * 128, m0 = by * 128;
    const int wm = (wave >> 1) * 64, wn = (wave & 1) * 64;
    const int lm = lane & 15, kq = lane >> 4;
    const int swz = (lm & 7) << 4;                  // read-side XOR (row&7 == lm&7)
    f32x4 acc[4][4] = {};

    for (int kb = 0; kb < K; kb += 64) {
        if (AGATHER) {
            // A rows gathered from emb via x (fp32 -> bf16), swizzled ds_write.
            #pragma unroll
            for (int it = 0; it < 8; ++it) {        // 2048 float4 chunks
                int chunk = it * 256 + tid;
                int row = chunk >> 4, kc = chunk & 15;
                int xi = xidx[m0 + row];
                xi = xi > 9999 ? 9999 : (xi < 0 ? 0 : xi);
                float4 a4 = *reinterpret_cast<const float4*>(&embp[(size_t)xi * 128 + kb + kc * 4]);
                ushort4 b4;
                b4.x = f2bf(a4.x); b4.y = f2bf(a4.y); b4.z = f2bf(a4.z); b4.w = f2bf(a4.w);
                int sb = (row * 128 + kc * 8) ^ ((row & 7) << 4);
                *reinterpret_cast<ushort4*>((char*)As + sb) = b4;
            }
        } else {
            #pragma unroll
            for (int seg = 0; seg < 4; ++seg) {     // 4KB per wave, 1KB per call
                int chunk = (wave * 4 + seg) * 64 + lane;   // 0..1023
                int L  = chunk * 16;                         // linear LDS byte
                int Ls = L ^ (((L >> 7) & 7) << 4);          // logical byte stored here
                int row = Ls >> 7, colb = Ls & 127;
                gload16(&A[(size_t)(m0 + row) * lda + kb + (colb >> 1)],
                        (char*)As + (wave * 4 + seg) * 1024);
            }
        }
        #pragma unroll
        for (int seg = 0; seg < 4; ++seg) {         // W bf16 via gload_lds
            int chunk = (wave * 4 + seg) * 64 + lane;
            int L  = chunk * 16;
            int Ls = L ^ (((L >> 7) & 7) << 4);
            int row = Ls >> 7, colb = Ls & 127;
            gload16(&W[(size_t)(n0 + row) * ldw + kb + (colb >> 1)],
                    (char*)Ws + (wave * 4 + seg) * 1024);
        }
        __syncthreads();                            // drains vmcnt (gload) + lgkmcnt
        #pragma unroll
        for (int k2 = 0; k2 < 2; ++k2) {
            bf16x8 af[4], wf[4];
            #pragma unroll
            for (int tt = 0; tt < 4; ++tt) {
                int Pa = (wm + tt * 16 + lm) * 128 + k2 * 64 + kq * 16;
                int Pw = (wn + tt * 16 + lm) * 128 + k2 * 64 + kq * 16;
                af[tt] = *reinterpret_cast<const bf16x8*>((const char*)As + (Pa ^ swz));
                wf[tt] = *reinterpret_cast<const bf16x8*>((const char*)Ws + (Pw ^ swz));
            }
            #pragma unroll
            for (int tm = 0; tm < 4; ++tm)
                #pragma unroll
                for (int tn = 0; tn < 4; ++tn)
                    acc[tm][tn] = __builtin_amdgcn_mfma_f32_16x16x32_bf16(af[tm], wf[tn], acc[tm][tn], 0, 0, 0);
        }
        __syncthreads();
    }
    float bn[4];
    #pragma unroll
    for (int tn = 0; tn < 4; ++tn) {
        int n = n0 + wn + tn * 16 + lm;
        float b = 0.f;
        if (n < N) {
            if (bias) b = bias[n];
            if (bhh_fold) {                         // fold bhh for r,z gate columns
                int c = n < 384 ? n : n - 384;
                if (c < 256) b += bhh_fold[n];
            }
        }
        bn[tn] = b;
    }
    #pragma unroll
    for (int tm = 0; tm < 4; ++tm) {
        int mbase = m0 + wm + tm * 16 + kq * 4;   // C/D: col=lane&15, row=quad*4+reg (m89-verified)
        #pragma unroll
        for (int tn = 0; tn < 4; ++tn) {
            int n = n0 + wn + tn * 16 + lm;
            if (n < N) {
                #pragma unroll
                for (int i = 0; i < 4; ++i) {
                    int m = mbase + i;
                    if (m < M) {
                        float v = acc[tm][tn][i] + bn[tn];
                        if (NTC) __builtin_nontemporal_store(v, &C[(size_t)m * ldc + n]);
                        else     C[(size_t)m * ldc + n] = v;
                    }
                }
            }
        }
    }
}

// ---------------------------------------------------------------- GRU scan (in-register gates)
// 8 blocks = dir*4 + batch_quarter (16 rows). 512 thr = 8 waves.
// Wave w computes n-tiles {w, 8+w, 16+w} => lane (kq,lm) holds ghr/ghz/ghn for
// j = w*16+lm, batch rows kq*4+0..3 IN ACC REGISTERS after MFMA. Nonlinearity
// fully in-register; only h round-trips LDS (double-buffered -> ONE lds_barrier/step).
// Time loop unrolled x2: gi register sets A/B, each reloaded 2 steps ahead ->
// ~2 steps of latency cover; loads stay in flight across the lgkmcnt-only barrier.
// Whh is PRE-CONVERTED bf16 (cvt_all) -> B-frag prologue is 12 vector loads.
__global__ __launch_bounds__(512) void gru_scan(const float* __restrict__ gi, int gi_tconst,
                                                const ushort* __restrict__ Whh,  // [2][384][128] bf16
                                                const float* __restrict__ bhh,   // [2][384] fp32
                                                ushort* __restrict__ y,          // [64][100][256] bf16 or null
                                                float* __restrict__ hf32,        // [64][512]
                                                ushort* __restrict__ hbf,        // [64][512] bf16 or null
                                                int hoff) {
    __shared__ __align__(16) ushort hbuf[2][16 * 136];   // bf16 h, [b][k] stride 136, double-buffered
    const int d = blockIdx.x >> 2, q = blockIdx.x & 3;
    const int tid = threadIdx.x;
    const int lane = tid & 63, w = tid >> 6;
    const int lm = lane & 15, kq = lane >> 4;
    const int j = w * 16 + lm;                            // this lane's hidden index

    for (int i = tid; i < 16 * 136; i += 512) hbuf[0][i] = 0;

    // B-frags for n-tiles {w, 8+w, 16+w}: lane's col = g*128 + j, k = kb*32 + kq*8 + idx.
    bf16x8 bfr[3][4];
    {
        const ushort* Wd = Whh + (size_t)d * 384 * 128;
        #pragma unroll
        for (int g = 0; g < 3; ++g)
            #pragma unroll
            for (int kb = 0; kb < 4; ++kb)
                bfr[g][kb] = *reinterpret_cast<const bf16x8*>(
                    &Wd[(size_t)(g * 128 + j) * 128 + kb * 32 + kq * 8]);
    }
    const float bhn = bhh[d * 384 + 256 + j];
    const bool rev = (d == 1);

    float hreg[4] = {0.f, 0.f, 0.f, 0.f};
    float grA[4], gzA[4], gnA[4], grB[4], gzB[4], gnB[4];
    {   // prologue: load gi for first two steps
        int t0 = rev ? 99 : 0, t1 = rev ? 98 : 1;
        #pragma unroll
        for (int r = 0; r < 4; ++r) {
            int b = q * 16 + kq * 4 + r;
            const float* g0 = gi_tconst ? gi + (size_t)b * 768 + d * 384
                                        : gi + ((size_t)b * 100 + t0) * 768 + d * 384;
            grA[r] = g0[j]; gzA[r] = g0[128 + j]; gnA[r] = g0[256 + j];
            const float* g1 = gi_tconst ? gi + (size_t)b * 768 + d * 384
                                        : gi + ((size_t)b * 100 + t1) * 768 + d * 384;
            grB[r] = g1[j]; gzB[r] = g1[128 + j]; gnB[r] = g1[256 + j];
        }
    }
    lds_barrier();

    auto step = [&](int ti, int pb, float (&gr)[4], float (&gz)[4], float (&gn)[4]) {
        const int t = rev ? 99 - ti : ti;
        const ushort* hb = hbuf[pb];
        bf16x8 afr[4];
        #pragma unroll
        for (int kb = 0; kb < 4; ++kb)
            afr[kb] = *reinterpret_cast<const bf16x8*>(&hb[lm * 136 + kb * 32 + kq * 8]);
        // gh = h @ Whh.T : six 2-deep acc chains (r,z,n x lo/hi K-half)
        f32x4 aR0 = {0,0,0,0}, aZ0 = {0,0,0,0}, aN0 = {0,0,0,0};
        f32x4 aR1 = {0,0,0,0}, aZ1 = {0,0,0,0}, aN1 = {0,0,0,0};
        aR0 = __builtin_amdgcn_mfma_f32_16x16x32_bf16(afr[0], bfr[0][0], aR0, 0, 0, 0);
        aZ0 = __builtin_amdgcn_mfma_f32_16x16x32_bf16(afr[0], bfr[1][0], aZ0, 0, 0, 0);
        aN0 = __builtin_amdgcn_mfma_f32_16x16x32_bf16(afr[0], bfr[2][0], aN0, 0, 0, 0);
        aR1 = __builtin_amdgcn_mfma_f32_16x16x32_bf16(afr[2], bfr[0][2], aR1, 0, 0, 0);
        aZ1 = __builtin_amdgcn_mfma_f32_16x16x32_bf16(afr[2], bfr[1][2], aZ1, 0, 0, 0);
        aN1 = __builtin_amdgcn_mfma_f32_16x16x32_bf16(afr[2], bfr[2][2], aN1, 0, 0, 0);
        aR0 = __builtin_amdgcn_mfma_f32_16x16x32_bf16(afr[1], bfr[0][1], aR0, 0, 0, 0);
        aZ0 = __builtin_amdgcn_mfma_f32_16x16x32_bf16(afr[1], bfr[1][1], aZ0, 0, 0, 0);
        aN0 = __builtin_amdgcn_mfma_f32_16x16x32_bf16(afr[1], bfr[2][1], aN0, 0, 0, 0);
        aR1 = __builtin_amdgcn_mfma_f32_16x16x32_bf16(afr[3], bfr[0][3], aR1, 0, 0, 0);
        aZ1 = __builtin_amdgcn_mfma_f32_16x16x32_bf16(afr[3], bfr[1][3], aZ1, 0, 0, 0);
        aN1 = __builtin_amdgcn_mfma_f32_16x16x32_bf16(afr[3], bfr[2][3], aN1, 0, 0, 0);
        // nonlinearity, fully in-register (gi already has bih + bhh_{r,z} folded)
        ushort* hw = hbuf[pb ^ 1];
        #pragma unroll
        for (int r = 0; r < 4; ++r) {
            float rr = sigm(gr[r] + aR0[r] + aR1[r]);
            float zz = sigm(gz[r] + aZ0[r] + aZ1[r]);
            float nn = tanh_f(gn[r] + rr * (aN0[r] + aN1[r] + bhn));
            float h = nn + zz * (hreg[r] - nn);
            hreg[r] = h;
            hw[(kq * 4 + r) * 136 + j] = f2bf(h);
            if (y) {
                int b = q * 16 + kq * 4 + r;
                y[((size_t)b * 100 + t) * 256 + d * 128 + j] = f2bf(h);
            }
        }
        // reload THIS set for step ti+2 (consumed ~2 steps from issue)
        if (!gi_tconst && ti + 2 < 100) {
            int tn2 = rev ? 99 - (ti + 2) : ti + 2;
            #pragma unroll
            for (int r = 0; r < 4; ++r) {
                int b = q * 16 + kq * 4 + r;
                const float* g = gi + ((size_t)b * 100 + tn2) * 768 + d * 384;
                gr[r] = g[j]; gz[r] = g[128 + j]; gn[r] = g[256 + j];
            }
        }
        lds_barrier();   // LDS-only: gi loads / y stores stay in flight
    };

    #pragma unroll 1
    for (int ti = 0; ti < 100; ti += 2) {
        step(ti,     0, grA, gzA, gnA);
        step(ti + 1, 1, grB, gzB, gnB);
    }

    #pragma unroll
    for (int r = 0; r < 4; ++r) {
        int b = q * 16 + kq * 4 + r;
        int col = hoff + d * 128 + j;   // torch hidden layout: [l0f,l0b,l1f,l1b]
        hf32[(size_t)b * 512 + col] = hreg[r];
        if (hbf) hbf[(size_t)b * 512 + col] = f2bf(hreg[r]);
    }
}

// ---------------------------------------------------------------- fc head: out = [enc_h, dec_h] @ fc_W.T + fc_b
__global__ __launch_bounds__(256) void fc_out(const float* __restrict__ ench,
                                              const float* __restrict__ dech,
                                              const float* __restrict__ W,
                                              const float* __restrict__ bias,
                                              float* __restrict__ out) {
    __shared__ float v[1024];
    int b = blockIdx.x, tid = threadIdx.x;
    for (int i = tid; i < 1024; i += 256)
        v[i] = (i < 512) ? ench[b * 512 + i] : dech[b * 512 + i - 512];
    __syncthreads();
    int wave = tid >> 6, lane = tid & 63;
    for (int c = wave; c < 20; c += 4) {
        float s = 0.f;
        for (int k = lane; k < 1024; k += 64) s += v[k] * W[c * 1024 + k];
        #pragma unroll
        for (int off = 32; off >= 1; off >>= 1) s += __shfl_xor(s, off, 64);
        if (lane == 0) out[b * 20 + c] = s + bias[c];
    }
}

// ---------------------------------------------------------------- launch
extern "C" void kernel_launch(void* const* d_in, const int* in_sizes, int n_in,
                              void* d_out, int out_size, void* d_ws, size_t ws_size,
                              hipStream_t stream) {
    const int*   x     = (const int*)  d_in[0];
    const float* emb   = (const float*)d_in[1];
    const float* eWih0 = (const float*)d_in[2];
    const float* eWhh0 = (const float*)d_in[3];
    const float* ebih0 = (const float*)d_in[4];
    const float* ebhh0 = (const float*)d_in[5];
    const float* eWih1 = (const float*)d_in[6];
    const float* eWhh1 = (const float*)d_in[7];
    const float* ebih1 = (const float*)d_in[8];
    const float* ebhh1 = (const float*)d_in[9];
    const float* dWih0 = (const float*)d_in[10];
    const float* dWhh0 = (const float*)d_in[11];
    const float* dbih0 = (const float*)d_in[12];
    const float* dbhh0 = (const float*)d_in[13];
    const float* dWih1 = (const float*)d_in[14];
    const float* dWhh1 = (const float*)d_in[15];
    const float* dbih1 = (const float*)d_in[16];
    const float* dbhh1 = (const float*)d_in[17];
    const float* fcW   = (const float*)d_in[18];
    const float* fcb   = (const float*)d_in[19];
    const float* recW  = (const float*)d_in[20];
    const float* recb  = (const float*)d_in[21];

    char* ws = (char*)d_ws;
    size_t off = 0;
    auto alloc = [&](size_t bytes) {
        char* p = ws + off;
        off = (off + bytes + 255) & ~(size_t)255;
        return p;
    };
    float*  gi    = (float*) alloc((size_t)6400 * 768 * 4);   // gate inputs (fp32, reused 3x)
    ushort* yA    = (ushort*)alloc((size_t)6400 * 256 * 2);   // enc l0 / dec l0 output seq (bf16)
    ushort* y1d   = (ushort*)alloc((size_t)6400 * 256 * 2);   // dec l1 output = rec_seq (bf16)
    ushort* wbuf  = (ushort*)alloc((size_t)3837952 * 2);      // bf16 weights (9 segments)
    float*  digi  = (float*) alloc((size_t)64 * 768 * 4);     // dec l0 time-constant gi
    float*  enchf = (float*) alloc((size_t)64 * 512 * 4);
    ushort* enchb = (ushort*)alloc((size_t)64 * 512 * 2);
    float*  dechf = (float*) alloc((size_t)64 * 512 * 4);
    alloc(65536);   // tail slack: OOB tile reads (N/M tails) stay inside ws
    (void)ws_size;

    ushort* w_e0   = wbuf;
    ushort* w_e1   = wbuf + 98304;
    ushort* w_d0   = wbuf + 294912;
    ushort* w_d1   = wbuf + 688128;
    ushort* w_rec  = wbuf + 884736;
    ushort* w_ehh0 = wbuf + 3444736;
    ushort* w_ehh1 = wbuf + 3543040;
    ushort* w_dhh0 = wbuf + 3641344;
    ushort* w_dhh1 = wbuf + 3739648;

    float* out_fc  = (float*)d_out;              // [64][20]
    float* out_rec = (float*)d_out + 1280;       // [64][100][10000]

    // one-shot weight conversion (4x Wih + recW + 4x Whh -> bf16), 479744 threads exactly
    cvt_all<<<1874, 256, 0, stream>>>(eWih0, eWih1, dWih0, dWih1, recW,
                                      eWhh0, eWhh1, dWhh0, dWhh1, wbuf);

    // encoder layer 0: A gathered from emb via x (bhh r,z folded into gi)
    gemm_bt<true, false, false><<<dim3(6, 50), 256, 0, stream>>>(nullptr, 128, w_e0, 128, ebih0, ebhh0,
                                                                 gi, 768, 6400, 768, 128, emb, x);
    gru_scan<<<8, 512, 0, stream>>>(gi, 0, w_ehh0, ebhh0, yA, enchf, enchb, 0);
    // encoder layer 1 (only final h needed)
    gemm_bt<false, false, true><<<dim3(6, 50), 256, 0, stream>>>(yA, 256, w_e1, 256, ebih1, ebhh1,
                                                                 gi, 768, 6400, 768, 256, nullptr, nullptr);
    gru_scan<<<8, 512, 0, stream>>>(gi, 0, w_ehh1, ebhh1, nullptr, enchf, enchb, 256);
    // decoder layer 0: broadcast enc_h -> gi constant over t
    gemm_bt<false, false, false><<<dim3(6, 1), 256, 0, stream>>>(enchb, 512, w_d0, 512, dbih0, dbhh0,
                                                                 digi, 768, 64, 768, 512, nullptr, nullptr);
    gru_scan<<<8, 512, 0, stream>>>(digi, 1, w_dhh0, dbhh0, yA, dechf, nullptr, 0);
    // decoder layer 1
    gemm_bt<false, false, true><<<dim3(6, 50), 256, 0, stream>>>(yA, 256, w_d1, 256, dbih1, dbhh1,
                                                                 gi, 768, 6400, 768, 256, nullptr, nullptr);
    gru_scan<<<8, 512, 0, stream>>>(gi, 0, w_dhh1, dbhh1, y1d, dechf, nullptr, 256);
    // reconstruction GEMM (gload_lds staging; XCD-swizzled blocks; NT C stores)
    gemm_bt<false, true, true><<<dim3(79, 50), 256, 0, stream>>>(y1d, 256, w_rec, 256, recb, nullptr,
                                                                 out_rec, 10000, 6400, 10000, 256, nullptr, nullptr);
    // fc head
    fc_out<<<64, 256, 0, stream>>>(enchf, dechf, fcW, fcb, out_fc);
}

// Round 8
// 914.173 us; speedup vs baseline: 1.1550x; 1.0823x over previous
//
#include <hip/hip_runtime.h>
#include <hip/hip_bf16.h>

// FSNet: embed -> bi-GRU(2) encoder -> broadcast -> bi-GRU(2) decoder
//        -> fc head (64x20) + reconstruction GEMM (64x100x10000)
// R8 changes vs R7 (989.4 us):
//  - gru_scan: y-stores moved AFTER the lds_barrier (register-sourced, no ordering
//    need) -> removed from the 8-wave barrier-arrival critical path; they overlap
//    the next step's ds_reads.
//  - gemm_bt epilogue: lane-paired float2 C-stores via __shfl_xor(v,1) (even lane
//    stores {self, neighbor}) -> halves store instructions + partial-line overhead.
//    N/ldc even everywhere -> pairs never straddle bounds checks.
// Output bitwise-identical to R7 -> absmax canary must stay 0.001953125.

typedef __bf16 bf16x8 __attribute__((ext_vector_type(8)));
typedef float f32x4 __attribute__((ext_vector_type(4)));
typedef float f32x2 __attribute__((ext_vector_type(2)));

__device__ __forceinline__ ushort f2bf(float f) {
    __hip_bfloat16 h = __float2bfloat16(f);   // RNE
    return *reinterpret_cast<ushort*>(&h);
}
__device__ __forceinline__ float sigm(float x) {
    return 1.f / (1.f + __expf(-x));
}
__device__ __forceinline__ float tanh_f(float x) {
    x = fminf(fmaxf(x, -15.f), 15.f);
    float e = __expf(2.f * x);
    return (e - 1.f) / (e + 1.f);
}
// LDS-only barrier: orders ds_write -> ds_read without draining vmcnt.
__device__ __forceinline__ void lds_barrier() {
    asm volatile("s_waitcnt lgkmcnt(0)" ::: "memory");
    __builtin_amdgcn_s_barrier();
}
// async global->LDS, 16B per lane; lds base is wave-uniform, HW adds lane*16.
__device__ __forceinline__ void gload16(const void* g, void* l) {
    __builtin_amdgcn_global_load_lds(
        (const __attribute__((address_space(1))) unsigned int*)g,
        (__attribute__((address_space(3))) unsigned int*)l, 16, 0, 0);
}

// ---------------------------------------------------------------- fp32 -> bf16, 9 segments, one dispatch
// dst layout (elements):
//  [eWih0:98304][eWih1:196608][dWih0:393216][dWih1:196608][recW:2560000]
//  [eWhh0:98304][eWhh1:98304][dWhh0:98304][dWhh1:98304]   total 3837952
__global__ __launch_bounds__(256) void cvt_all(const float* __restrict__ s0,
                                               const float* __restrict__ s1,
                                               const float* __restrict__ s2,
                                               const float* __restrict__ s3,
                                               const float* __restrict__ s4,
                                               const float* __restrict__ s5,
                                               const float* __restrict__ s6,
                                               const float* __restrict__ s7,
                                               const float* __restrict__ s8,
                                               ushort* __restrict__ dst) {
    int i = blockIdx.x * 256 + threadIdx.x;         // 479744 threads exactly
    size_t e = (size_t)i * 8;
    const float* s; size_t off;
    if      (e < 98304)   { s = s0; off = e; }
    else if (e < 294912)  { s = s1; off = e - 98304; }
    else if (e < 688128)  { s = s2; off = e - 294912; }
    else if (e < 884736)  { s = s3; off = e - 688128; }
    else if (e < 3444736) { s = s4; off = e - 884736; }
    else if (e < 3543040) { s = s5; off = e - 3444736; }
    else if (e < 3641344) { s = s6; off = e - 3543040; }
    else if (e < 3739648) { s = s7; off = e - 3641344; }
    else                  { s = s8; off = e - 3739648; }
    const float* p = s + off;
    ushort4 lo, hi;
    lo.x = f2bf(p[0]); lo.y = f2bf(p[1]); lo.z = f2bf(p[2]); lo.w = f2bf(p[3]);
    hi.x = f2bf(p[4]); hi.y = f2bf(p[5]); hi.z = f2bf(p[6]); hi.w = f2bf(p[7]);
    ushort* d = dst + e;
    *reinterpret_cast<ushort4*>(d)     = lo;
    *reinterpret_cast<ushort4*>(d + 4) = hi;
}

// ---------------------------------------------------------------- GEMM C = A @ W.T + bias (fp32 out)
// A: [M][K] bf16 (AGATHER: emb rows via x, reg-staged). W: [N][K] bf16, gload_lds.
// 128x128 tile, 4 waves, mfma 16x16x32 bf16. LDS linear [128][64]u16 with
// byte ^= ((row&7)<<4) swizzle (write via pre-swizzled gload source; read swizzled).
// XSWZ: bijective XCD-contiguous block remap (m204) for A/W L2 locality.
// Epilogue: lane-paired float2 stores (even lane stores {self, shfl_xor(v,1)}).
// OOB tile rows (N tail, M=64 case) read garbage from within ws -- never stored.
// bhh_fold (optional, N=768 GRU case): adds bhh[n] for gate cols (n%384)<256 (r,z biases).
template <bool AGATHER, bool NTC, bool XSWZ>
__global__ __launch_bounds__(256) void gemm_bt(const ushort* __restrict__ A, int lda,
                                               const ushort* __restrict__ W, int ldw,
                                               const float* __restrict__ bias,
                                               const float* __restrict__ bhh_fold,
                                               float* __restrict__ C, int ldc,
                                               int M, int N, int K,
                                               const float* __restrict__ embp,
                                               const int* __restrict__ xidx) {
    __shared__ __align__(16) ushort As[128 * 64];   // linear, 16KB
    __shared__ __align__(16) ushort Ws[128 * 64];
    const int tid = threadIdx.x;
    const int lane = tid & 63, wave = tid >> 6;
    int bx = blockIdx.x, by = blockIdx.y;
    if (XSWZ) {
        // bijective XCD swizzle (m204): consecutive HW-dispatch ids round-robin
        // XCDs; give each XCD a contiguous range of logical blocks.
        int nx = gridDim.x;
        int nwg = nx * gridDim.y;
        int bid = by * nx + bx;
        int q = nwg >> 3, r = nwg & 7;
        int xcd = bid & 7, loc = bid >> 3;
        int swz = (xcd < r ? xcd * (q + 1) : r * (q + 1) + (xcd - r) * q) + loc;
        bx = swz % nx;
        by = swz / nx;
    }
    const int n0 = bx * 128, m0 = by * 128;
    const int wm = (wave >> 1) * 64, wn = (wave & 1) * 64;
    const int lm = lane & 15, kq = lane >> 4;
    const int swz = (lm & 7) << 4;                  // read-side XOR (row&7 == lm&7)
    f32x4 acc[4][4] = {};

    for (int kb = 0; kb < K; kb += 64) {
        if (AGATHER) {
            // A rows gathered from emb via x (fp32 -> bf16), swizzled ds_write.
            #pragma unroll
            for (int it = 0; it < 8; ++it) {        // 2048 float4 chunks
                int chunk = it * 256 + tid;
                int row = chunk >> 4, kc = chunk & 15;
                int xi = xidx[m0 + row];
                xi = xi > 9999 ? 9999 : (xi < 0 ? 0 : xi);
                float4 a4 = *reinterpret_cast<const float4*>(&embp[(size_t)xi * 128 + kb + kc * 4]);
                ushort4 b4;
                b4.x = f2bf(a4.x); b4.y = f2bf(a4.y); b4.z = f2bf(a4.z); b4.w = f2bf(a4.w);
                int sb = (row * 128 + kc * 8) ^ ((row & 7) << 4);
                *reinterpret_cast<ushort4*>((char*)As + sb) = b4;
            }
        } else {
            #pragma unroll
            for (int seg = 0; seg < 4; ++seg) {     // 4KB per wave, 1KB per call
                int chunk = (wave * 4 + seg) * 64 + lane;   // 0..1023
                int L  = chunk * 16;                         // linear LDS byte
                int Ls = L ^ (((L >> 7) & 7) << 4);          // logical byte stored here
                int row = Ls >> 7, colb = Ls & 127;
                gload16(&A[(size_t)(m0 + row) * lda + kb + (colb >> 1)],
                        (char*)As + (wave * 4 + seg) * 1024);
            }
        }
        #pragma unroll
        for (int seg = 0; seg < 4; ++seg) {         // W bf16 via gload_lds
            int chunk = (wave * 4 + seg) * 64 + lane;
            int L  = chunk * 16;
            int Ls = L ^ (((L >> 7) & 7) << 4);
            int row = Ls >> 7, colb = Ls & 127;
            gload16(&W[(size_t)(n0 + row) * ldw + kb + (colb >> 1)],
                    (char*)Ws + (wave * 4 + seg) * 1024);
        }
        __syncthreads();                            // drains vmcnt (gload) + lgkmcnt
        #pragma unroll
        for (int k2 = 0; k2 < 2; ++k2) {
            bf16x8 af[4], wf[4];
            #pragma unroll
            for (int tt = 0; tt < 4; ++tt) {
                int Pa = (wm + tt * 16 + lm) * 128 + k2 * 64 + kq * 16;
                int Pw = (wn + tt * 16 + lm) * 128 + k2 * 64 + kq * 16;
                af[tt] = *reinterpret_cast<const bf16x8*>((const char*)As + (Pa ^ swz));
                wf[tt] = *reinterpret_cast<const bf16x8*>((const char*)Ws + (Pw ^ swz));
            }
            #pragma unroll
            for (int tm = 0; tm < 4; ++tm)
                #pragma unroll
                for (int tn = 0; tn < 4; ++tn)
                    acc[tm][tn] = __builtin_amdgcn_mfma_f32_16x16x32_bf16(af[tm], wf[tn], acc[tm][tn], 0, 0, 0);
        }
        __syncthreads();
    }
    float bn[4];
    #pragma unroll
    for (int tn = 0; tn < 4; ++tn) {
        int n = n0 + wn + tn * 16 + lm;
        float b = 0.f;
        if (n < N) {
            if (bias) b = bias[n];
            if (bhh_fold) {                         // fold bhh for r,z gate columns
                int c = n < 384 ? n : n - 384;
                if (c < 256) b += bhh_fold[n];
            }
        }
        bn[tn] = b;
    }
    // lane-paired epilogue: even lm stores float2 {v(n), v(n+1)}; N,ldc even ->
    // pair bounds are uniform; values bitwise-identical to scalar path.
    #pragma unroll
    for (int tm = 0; tm < 4; ++tm) {
        int mbase = m0 + wm + tm * 16 + kq * 4;   // C/D: col=lane&15, row=quad*4+reg (m89-verified)
        #pragma unroll
        for (int tn = 0; tn < 4; ++tn) {
            int n = n0 + wn + tn * 16 + lm;
            #pragma unroll
            for (int i = 0; i < 4; ++i) {
                float v = acc[tm][tn][i] + bn[tn];
                float vnb = __shfl_xor(v, 1, 64);   // neighbor lane's value (n^1)
                int m = mbase + i;
                if (!(lm & 1) && n < N && m < M) {
                    f32x2 p; p[0] = v; p[1] = vnb;
                    if (NTC) __builtin_nontemporal_store(p, (f32x2*)&C[(size_t)m * ldc + n]);
                    else     *reinterpret_cast<f32x2*>(&C[(size_t)m * ldc + n]) = p;
                }
            }
        }
    }
}

// ---------------------------------------------------------------- GRU scan (in-register gates)
// 8 blocks = dir*4 + batch_quarter (16 rows). 512 thr = 8 waves.
// Wave w computes n-tiles {w, 8+w, 16+w} => lane (kq,lm) holds ghr/ghz/ghn for
// j = w*16+lm, batch rows kq*4+0..3 IN ACC REGISTERS after MFMA. Nonlinearity
// fully in-register; only h round-trips LDS (double-buffered -> ONE lds_barrier/step).
// Time loop unrolled x2: gi register sets A/B, each reloaded 2 steps ahead.
// y-stores issued AFTER the barrier (off the 8-wave arrival critical path).
// Whh is PRE-CONVERTED bf16 (cvt_all) -> B-frag prologue is 12 vector loads.
__global__ __launch_bounds__(512) void gru_scan(const float* __restrict__ gi, int gi_tconst,
                                                const ushort* __restrict__ Whh,  // [2][384][128] bf16
                                                const float* __restrict__ bhh,   // [2][384] fp32
                                                ushort* __restrict__ y,          // [64][100][256] bf16 or null
                                                float* __restrict__ hf32,        // [64][512]
                                                ushort* __restrict__ hbf,        // [64][512] bf16 or null
                                                int hoff) {
    __shared__ __align__(16) ushort hbuf[2][16 * 136];   // bf16 h, [b][k] stride 136, double-buffered
    const int d = blockIdx.x >> 2, q = blockIdx.x & 3;
    const int tid = threadIdx.x;
    const int lane = tid & 63, w = tid >> 6;
    const int lm = lane & 15, kq = lane >> 4;
    const int j = w * 16 + lm;                            // this lane's hidden index

    for (int i = tid; i < 16 * 136; i += 512) hbuf[0][i] = 0;

    // B-frags for n-tiles {w, 8+w, 16+w}: lane's col = g*128 + j, k = kb*32 + kq*8 + idx.
    bf16x8 bfr[3][4];
    {
        const ushort* Wd = Whh + (size_t)d * 384 * 128;
        #pragma unroll
        for (int g = 0; g < 3; ++g)
            #pragma unroll
            for (int kb = 0; kb < 4; ++kb)
                bfr[g][kb] = *reinterpret_cast<const bf16x8*>(
                    &Wd[(size_t)(g * 128 + j) * 128 + kb * 32 + kq * 8]);
    }
    const float bhn = bhh[d * 384 + 256 + j];
    const bool rev = (d == 1);

    float hreg[4] = {0.f, 0.f, 0.f, 0.f};
    float grA[4], gzA[4], gnA[4], grB[4], gzB[4], gnB[4];
    {   // prologue: load gi for first two steps
        int t0 = rev ? 99 : 0, t1 = rev ? 98 : 1;
        #pragma unroll
        for (int r = 0; r < 4; ++r) {
            int b = q * 16 + kq * 4 + r;
            const float* g0 = gi_tconst ? gi + (size_t)b * 768 + d * 384
                                        : gi + ((size_t)b * 100 + t0) * 768 + d * 384;
            grA[r] = g0[j]; gzA[r] = g0[128 + j]; gnA[r] = g0[256 + j];
            const float* g1 = gi_tconst ? gi + (size_t)b * 768 + d * 384
                                        : gi + ((size_t)b * 100 + t1) * 768 + d * 384;
            grB[r] = g1[j]; gzB[r] = g1[128 + j]; gnB[r] = g1[256 + j];
        }
    }
    lds_barrier();

    auto step = [&](int ti, int pb, float (&gr)[4], float (&gz)[4], float (&gn)[4]) {
        const int t = rev ? 99 - ti : ti;
        const ushort* hb = hbuf[pb];
        bf16x8 afr[4];
        #pragma unroll
        for (int kb = 0; kb < 4; ++kb)
            afr[kb] = *reinterpret_cast<const bf16x8*>(&hb[lm * 136 + kb * 32 + kq * 8]);
        // gh = h @ Whh.T : six 2-deep acc chains (r,z,n x lo/hi K-half)
        f32x4 aR0 = {0,0,0,0}, aZ0 = {0,0,0,0}, aN0 = {0,0,0,0};
        f32x4 aR1 = {0,0,0,0}, aZ1 = {0,0,0,0}, aN1 = {0,0,0,0};
        aR0 = __builtin_amdgcn_mfma_f32_16x16x32_bf16(afr[0], bfr[0][0], aR0, 0, 0, 0);
        aZ0 = __builtin_amdgcn_mfma_f32_16x16x32_bf16(afr[0], bfr[1][0], aZ0, 0, 0, 0);
        aN0 = __builtin_amdgcn_mfma_f32_16x16x32_bf16(afr[0], bfr[2][0], aN0, 0, 0, 0);
        aR1 = __builtin_amdgcn_mfma_f32_16x16x32_bf16(afr[2], bfr[0][2], aR1, 0, 0, 0);
        aZ1 = __builtin_amdgcn_mfma_f32_16x16x32_bf16(afr[2], bfr[1][2], aZ1, 0, 0, 0);
        aN1 = __builtin_amdgcn_mfma_f32_16x16x32_bf16(afr[2], bfr[2][2], aN1, 0, 0, 0);
        aR0 = __builtin_amdgcn_mfma_f32_16x16x32_bf16(afr[1], bfr[0][1], aR0, 0, 0, 0);
        aZ0 = __builtin_amdgcn_mfma_f32_16x16x32_bf16(afr[1], bfr[1][1], aZ0, 0, 0, 0);
        aN0 = __builtin_amdgcn_mfma_f32_16x16x32_bf16(afr[1], bfr[2][1], aN0, 0, 0, 0);
        aR1 = __builtin_amdgcn_mfma_f32_16x16x32_bf16(afr[3], bfr[0][3], aR1, 0, 0, 0);
        aZ1 = __builtin_amdgcn_mfma_f32_16x16x32_bf16(afr[3], bfr[1][3], aZ1, 0, 0, 0);
        aN1 = __builtin_amdgcn_mfma_f32_16x16x32_bf16(afr[3], bfr[2][3], aN1, 0, 0, 0);
        // nonlinearity, fully in-register (gi already has bih + bhh_{r,z} folded)
        ushort* hw = hbuf[pb ^ 1];
        ushort yv[4];
        #pragma unroll
        for (int r = 0; r < 4; ++r) {
            float rr = sigm(gr[r] + aR0[r] + aR1[r]);
            float zz = sigm(gz[r] + aZ0[r] + aZ1[r]);
            float nn = tanh_f(gn[r] + rr * (aN0[r] + aN1[r] + bhn));
            float h = nn + zz * (hreg[r] - nn);
            hreg[r] = h;
            yv[r] = f2bf(h);
            hw[(kq * 4 + r) * 136 + j] = yv[r];
        }
        // reload THIS set for step ti+2 (consumed ~2 steps from issue)
        if (!gi_tconst && ti + 2 < 100) {
            int tn2 = rev ? 99 - (ti + 2) : ti + 2;
            #pragma unroll
            for (int r = 0; r < 4; ++r) {
                int b = q * 16 + kq * 4 + r;
                const float* g = gi + ((size_t)b * 100 + tn2) * 768 + d * 384;
                gr[r] = g[j]; gz[r] = g[128 + j]; gn[r] = g[256 + j];
            }
        }
        lds_barrier();   // LDS-only: gi loads stay in flight
        // y-stores AFTER the barrier: off the arrival path, overlap next step's ds_reads
        if (y) {
            #pragma unroll
            for (int r = 0; r < 4; ++r) {
                int b = q * 16 + kq * 4 + r;
                y[((size_t)b * 100 + t) * 256 + d * 128 + j] = yv[r];
            }
        }
    };

    #pragma unroll 1
    for (int ti = 0; ti < 100; ti += 2) {
        step(ti,     0, grA, gzA, gnA);
        step(ti + 1, 1, grB, gzB, gnB);
    }

    #pragma unroll
    for (int r = 0; r < 4; ++r) {
        int b = q * 16 + kq * 4 + r;
        int col = hoff + d * 128 + j;   // torch hidden layout: [l0f,l0b,l1f,l1b]
        hf32[(size_t)b * 512 + col] = hreg[r];
        if (hbf) hbf[(size_t)b * 512 + col] = f2bf(hreg[r]);
    }
}

// ---------------------------------------------------------------- fc head: out = [enc_h, dec_h] @ fc_W.T + fc_b
__global__ __launch_bounds__(256) void fc_out(const float* __restrict__ ench,
                                              const float* __restrict__ dech,
                                              const float* __restrict__ W,
                                              const float* __restrict__ bias,
                                              float* __restrict__ out) {
    __shared__ float v[1024];
    int b = blockIdx.x, tid = threadIdx.x;
    for (int i = tid; i < 1024; i += 256)
        v[i] = (i < 512) ? ench[b * 512 + i] : dech[b * 512 + i - 512];
    __syncthreads();
    int wave = tid >> 6, lane = tid & 63;
    for (int c = wave; c < 20; c += 4) {
        float s = 0.f;
        for (int k = lane; k < 1024; k += 64) s += v[k] * W[c * 1024 + k];
        #pragma unroll
        for (int off = 32; off >= 1; off >>= 1) s += __shfl_xor(s, off, 64);
        if (lane == 0) out[b * 20 + c] = s + bias[c];
    }
}

// ---------------------------------------------------------------- launch
extern "C" void kernel_launch(void* const* d_in, const int* in_sizes, int n_in,
                              void* d_out, int out_size, void* d_ws, size_t ws_size,
                              hipStream_t stream) {
    const int*   x     = (const int*)  d_in[0];
    const float* emb   = (const float*)d_in[1];
    const float* eWih0 = (const float*)d_in[2];
    const float* eWhh0 = (const float*)d_in[3];
    const float* ebih0 = (const float*)d_in[4];
    const float* ebhh0 = (const float*)d_in[5];
    const float* eWih1 = (const float*)d_in[6];
    const float* eWhh1 = (const float*)d_in[7];
    const float* ebih1 = (const float*)d_in[8];
    const float* ebhh1 = (const float*)d_in[9];
    const float* dWih0 = (const float*)d_in[10];
    const float* dWhh0 = (const float*)d_in[11];
    const float* dbih0 = (const float*)d_in[12];
    const float* dbhh0 = (const float*)d_in[13];
    const float* dWih1 = (const float*)d_in[14];
    const float* dWhh1 = (const float*)d_in[15];
    const float* dbih1 = (const float*)d_in[16];
    const float* dbhh1 = (const float*)d_in[17];
    const float* fcW   = (const float*)d_in[18];
    const float* fcb   = (const float*)d_in[19];
    const float* recW  = (const float*)d_in[20];
    const float* recb  = (const float*)d_in[21];

    char* ws = (char*)d_ws;
    size_t off = 0;
    auto alloc = [&](size_t bytes) {
        char* p = ws + off;
        off = (off + bytes + 255) & ~(size_t)255;
        return p;
    };
    float*  gi    = (float*) alloc((size_t)6400 * 768 * 4);   // gate inputs (fp32, reused 3x)
    ushort* yA    = (ushort*)alloc((size_t)6400 * 256 * 2);   // enc l0 / dec l0 output seq (bf16)
    ushort* y1d   = (ushort*)alloc((size_t)6400 * 256 * 2);   // dec l1 output = rec_seq (bf16)
    ushort* wbuf  = (ushort*)alloc((size_t)3837952 * 2);      // bf16 weights (9 segments)
    float*  digi  = (float*) alloc((size_t)64 * 768 * 4);     // dec l0 time-constant gi
    float*  enchf = (float*) alloc((size_t)64 * 512 * 4);
    ushort* enchb = (ushort*)alloc((size_t)64 * 512 * 2);
    float*  dechf = (float*) alloc((size_t)64 * 512 * 4);
    alloc(65536);   // tail slack: OOB tile reads (N/M tails) stay inside ws
    (void)ws_size;

    ushort* w_e0   = wbuf;
    ushort* w_e1   = wbuf + 98304;
    ushort* w_d0   = wbuf + 294912;
    ushort* w_d1   = wbuf + 688128;
    ushort* w_rec  = wbuf + 884736;
    ushort* w_ehh0 = wbuf + 3444736;
    ushort* w_ehh1 = wbuf + 3543040;
    ushort* w_dhh0 = wbuf + 3641344;
    ushort* w_dhh1 = wbuf + 3739648;

    float* out_fc  = (float*)d_out;              // [64][20]
    float* out_rec = (float*)d_out + 1280;       // [64][100][10000]

    // one-shot weight conversion (4x Wih + recW + 4x Whh -> bf16), 479744 threads exactly
    cvt_all<<<1874, 256, 0, stream>>>(eWih0, eWih1, dWih0, dWih1, recW,
                                      eWhh0, eWhh1, dWhh0, dWhh1, wbuf);

    // encoder layer 0: A gathered from emb via x (bhh r,z folded into gi)
    gemm_bt<true, false, false><<<dim3(6, 50), 256, 0, stream>>>(nullptr, 128, w_e0, 128, ebih0, ebhh0,
                                                                 gi, 768, 6400, 768, 128, emb, x);
    gru_scan<<<8, 512, 0, stream>>>(gi, 0, w_ehh0, ebhh0, yA, enchf, enchb, 0);
    // encoder layer 1 (only final h needed)
    gemm_bt<false, false, true><<<dim3(6, 50), 256, 0, stream>>>(yA, 256, w_e1, 256, ebih1, ebhh1,
                                                                 gi, 768, 6400, 768, 256, nullptr, nullptr);
    gru_scan<<<8, 512, 0, stream>>>(gi, 0, w_ehh1, ebhh1, nullptr, enchf, enchb, 256);
    // decoder layer 0: broadcast enc_h -> gi constant over t
    gemm_bt<false, false, false><<<dim3(6, 1), 256, 0, stream>>>(enchb, 512, w_d0, 512, dbih0, dbhh0,
                                                                 digi, 768, 64, 768, 512, nullptr, nullptr);
    gru_scan<<<8, 512, 0, stream>>>(digi, 1, w_dhh0, dbhh0, yA, dechf, nullptr, 0);
    // decoder layer 1
    gemm_bt<false, false, true><<<dim3(6, 50), 256, 0, stream>>>(yA, 256, w_d1, 256, dbih1, dbhh1,
                                                                 gi, 768, 6400, 768, 256, nullptr, nullptr);
    gru_scan<<<8, 512, 0, stream>>>(gi, 0, w_dhh1, dbhh1, y1d, dechf, nullptr, 256);
    // reconstruction GEMM (gload_lds staging; XCD-swizzled blocks; NT C stores)
    gemm_bt<false, true, true><<<dim3(79, 50), 256, 0, stream>>>(y1d, 256, w_rec, 256, recb, nullptr,
                                                                 out_rec, 10000, 6400, 10000, 256, nullptr, nullptr);
    // fc head
    fc_out<<<64, 256, 0, stream>>>(enchf, dechf, fcW, fcb, out_fc);
}